// Round 1
// baseline (120.982 us; speedup 1.0000x reference)
//
#include <hip/hip_runtime.h>
#include <hip/hip_bf16.h>

// Problem shape (fixed by setup_inputs): B=2, H=8, T=1024, P=64
#define TDIM 1024
#define PDIM 64
#define BHN  16     // B*H
#define NCH  16     // chunks along T
#define CHS  64     // chunk size (NCH*CHS == TDIM)

typedef __bf16 bf16_t;
typedef bf16_t bf16x8 __attribute__((ext_vector_type(8)));
typedef float  floatx4 __attribute__((ext_vector_type(4)));

__device__ __forceinline__ floatx4 mfma16(bf16x8 a, bf16x8 b, floatx4 c) {
    return __builtin_amdgcn_mfma_f32_16x16x32_bf16(a, b, c, 0, 0, 0);
}

// ---------------------------------------------------------------------------
// A1: per-(bh, chunk) stats: chunk max of K and chunk sum of exp(2K), per p.
// grid = BHN*NCH blocks of 64 threads (lane = p).
// ---------------------------------------------------------------------------
__global__ __launch_bounds__(64) void stats_kernel(
        const float* __restrict__ K,
        float* __restrict__ cmax, float* __restrict__ csum) {
    int bh = blockIdx.x >> 4;
    int c  = blockIdx.x & 15;
    int p  = threadIdx.x;
    const float* Kb = K + (size_t)bh * TDIM * PDIM;
    float m = -INFINITY, s = 0.f;
    int t0 = c * CHS;
    for (int tl = 0; tl < CHS; ++tl) {
        float k = Kb[(t0 + tl) * PDIM + p];
        m = fmaxf(m, k);
        float ek = __expf(k);
        s += ek * ek;
    }
    cmax[(bh * NCH + c) * PDIM + p] = m;
    csum[(bh * NCH + c) * PDIM + p] = s;
}

// ---------------------------------------------------------------------------
// A2: seeded within-chunk sequential scan. Emits:
//   W[bh][t][p]  = bf16( exp(Q - m_cum) )        (natural layout)
//   U[bh][t][p]  = bf16( V * exp(K) )            (natural layout)
//   Kft[bh][q][t]= bf16( exp(K[t][q]) )          (TRANSPOSED, via LDS tile)
//   den[bh][t]   = fp32 sum_p W*S2cum            (wave-reduced)
// grid = BHN*NCH blocks of 64 threads (lane = p).
// ---------------------------------------------------------------------------
__global__ __launch_bounds__(64) void feat_kernel(
        const float* __restrict__ Q, const float* __restrict__ K,
        const float* __restrict__ V,
        const float* __restrict__ cmax, const float* __restrict__ csum,
        bf16_t* __restrict__ W, bf16_t* __restrict__ U,
        bf16_t* __restrict__ Kft, float* __restrict__ den) {
    int bh = blockIdx.x >> 4;
    int c  = blockIdx.x & 15;
    int p  = threadIdx.x;
    size_t base = (size_t)bh * TDIM * PDIM;
    const float* Qb = Q + base;
    const float* Kb = K + base;
    const float* Vb = V + base;

    float m = -INFINITY, s = 0.f;
    for (int cc = 0; cc < c; ++cc) {
        m = fmaxf(m, cmax[(bh * NCH + cc) * PDIM + p]);
        s += csum[(bh * NCH + cc) * PDIM + p];
    }

    __shared__ bf16_t tile[CHS][PDIM + 1];  // [t_local][p], padded vs bank conflicts
    int t0 = c * CHS;
    for (int tl = 0; tl < CHS; ++tl) {
        int t = t0 + tl;
        float k = Kb[t * PDIM + p];
        float q = Qb[t * PDIM + p];
        float v = Vb[t * PDIM + p];
        m = fmaxf(m, k);
        float ek = __expf(k);
        s += ek * ek;                      // running sum of exp(2K)
        float w = __expf(q - m);
        W[base + t * PDIM + p] = (bf16_t)w;
        U[base + t * PDIM + p] = (bf16_t)(v * ek);
        tile[tl][p] = (bf16_t)ek;
        // den[t] = sum_p w * S2cum  (fp32, exact weights)
        float d = w * s;
        for (int off = 32; off > 0; off >>= 1) d += __shfl_xor(d, off);
        if (p == 0) den[bh * TDIM + t] = d;
    }
    __syncthreads();
    // transposed write-out: Kft[bh][qq][t0 + lane] = exp(K[t0+lane][qq])
    for (int qq = 0; qq < PDIM; ++qq) {
        Kft[((size_t)bh * PDIM + qq) * TDIM + t0 + p] = tile[p][qq];
    }
}

// ---------------------------------------------------------------------------
// B: per-(bh, 64-row tile) causal double matmul.
//   phase1: C[t][t'] = sum_p W[t][p]*U[t'][p]       (MFMA NT, k = p)
//   mask + C -> LDS (bf16)
//   phase2: Y[t][q] += sum_t' C[t][t']*Kft[q][t']   (MFMA NT, k = t')
//   epilogue: Y /= (den + eps), store to out[b][t][h*64+q]
// grid = BHN*16 blocks of 256 threads (4 waves; wave w owns t-strip [16w,16w+16)).
// ---------------------------------------------------------------------------
__global__ __launch_bounds__(256) void attn_kernel(
        const bf16_t* __restrict__ W, const bf16_t* __restrict__ U,
        const bf16_t* __restrict__ Kft, const float* __restrict__ den,
        float* __restrict__ out) {
    int bh  = blockIdx.x & 15;
    int i   = blockIdx.x >> 4;   // row tile index 0..15
    int tid = threadIdx.x;
    int wave = tid >> 6, lane = tid & 63;
    int lq = lane & 15, qd = lane >> 4;
    int b = bh >> 3, h = bh & 7;

    // rows padded to 72 bf16 (144 B): keeps ds_read_b128 fragment reads
    // spread over all 32 banks; 144 is a multiple of 16 so b128 stays aligned.
    __shared__ bf16_t Wt[64][72];
    __shared__ bf16_t Ut[64][72];
    __shared__ bf16_t Kt[64][72];
    __shared__ bf16_t Ct[64][72];
    __shared__ float  denb[64];

    size_t base = (size_t)bh * TDIM * PDIM;

    // stage W row-tile (8 KB contiguous) + den tile
    {
        const int4* gs = (const int4*)(W + base + (size_t)i * 64 * PDIM);
        for (int r = 0; r < 2; ++r) {
            int idx = tid + r * 256;
            int q = idx >> 3, s = idx & 7;
            *(int4*)&Wt[q][s * 8] = gs[idx];
        }
        if (tid < 64) denb[tid] = den[bh * TDIM + i * 64 + tid];
    }

    floatx4 acc[4];
    for (int j = 0; j < 4; ++j) acc[j] = (floatx4){0.f, 0.f, 0.f, 0.f};

    for (int kt = 0; kt <= i; ++kt) {
        __syncthreads();   // protect Ut/Kt (and first-iter Wt) vs prior phase2
        // stage U tile (contiguous) and Kft tile (strided rows of 128 B)
        const int4* us = (const int4*)(U + base + (size_t)kt * 64 * PDIM);
        for (int r = 0; r < 2; ++r) {
            int idx = tid + r * 256;
            int q = idx >> 3, s = idx & 7;
            *(int4*)&Ut[q][s * 8] = us[idx];
            const int4* ks2 =
                (const int4*)(Kft + ((size_t)bh * PDIM + q) * TDIM + kt * 64);
            *(int4*)&Kt[q][s * 8] = ks2[s];
        }
        __syncthreads();

        // ---- phase 1: C strip (16 rows) = W_strip . U^T ----
        // A-frag: A[m=lane&15][k=quad*8+j]; B-frag: B[k=quad*8+j][n=lane&15]
        bf16x8 a0 = *(const bf16x8*)&Wt[wave * 16 + lq][qd * 8];
        bf16x8 a1 = *(const bf16x8*)&Wt[wave * 16 + lq][32 + qd * 8];
        floatx4 cc[4];
        for (int j = 0; j < 4; ++j) {
            bf16x8 b0 = *(const bf16x8*)&Ut[j * 16 + lq][qd * 8];
            bf16x8 b1 = *(const bf16x8*)&Ut[j * 16 + lq][32 + qd * 8];
            floatx4 t = (floatx4){0.f, 0.f, 0.f, 0.f};
            t = mfma16(a0, b0, t);
            t = mfma16(a1, b1, t);
            cc[j] = t;
        }

        // ---- causal mask + C -> LDS (C/D layout: row=quad*4+reg, col=lane&15)
        for (int j = 0; j < 4; ++j) {
            for (int r = 0; r < 4; ++r) {
                int trow = wave * 16 + qd * 4 + r;   // t within block tile
                int tcol = j * 16 + lq;              // t' within k tile
                float v = cc[j][r];
                if (kt == i && tcol > trow) v = 0.f; // strictly-future masked
                Ct[trow][tcol] = (bf16_t)v;
            }
        }
        // no __syncthreads needed: each wave reads back only its own strip;
        // compiler inserts the lgkmcnt wait for the same-wave LDS dependency.

        // ---- phase 2: Y_strip += C_strip . Kf  (A from Ct, B from Kt) ----
        for (int ks = 0; ks < 2; ++ks) {
            bf16x8 ca = *(const bf16x8*)&Ct[wave * 16 + lq][ks * 32 + qd * 8];
            for (int j = 0; j < 4; ++j) {
                bf16x8 kb = *(const bf16x8*)&Kt[j * 16 + lq][ks * 32 + qd * 8];
                acc[j] = mfma16(ca, kb, acc[j]);
            }
        }
    }

    // ---- epilogue: divide by den, store (out[b][t][h*64+q]) ----
    for (int j = 0; j < 4; ++j) {
        for (int r = 0; r < 4; ++r) {
            int trow = wave * 16 + qd * 4 + r;
            int tg = i * 64 + trow;
            float y = acc[j][r] / (denb[trow] + 1e-6f);
            out[((size_t)b * TDIM + tg) * (8 * PDIM) + h * PDIM + (j * 16 + lq)] = y;
        }
    }
}

// ---------------------------------------------------------------------------
extern "C" void kernel_launch(void* const* d_in, const int* in_sizes, int n_in,
                              void* d_out, int out_size, void* d_ws, size_t ws_size,
                              hipStream_t stream) {
    const float* Q = (const float*)d_in[0];
    const float* K = (const float*)d_in[1];
    const float* V = (const float*)d_in[2];
    float* out = (float*)d_out;

    // workspace layout (~6.2 MB total)
    bf16_t* Wf   = (bf16_t*)d_ws;                       // 2 MB
    bf16_t* Uf   = Wf + (size_t)BHN * TDIM * PDIM;      // 2 MB
    bf16_t* Kft  = Uf + (size_t)BHN * TDIM * PDIM;      // 2 MB
    float*  den  = (float*)(Kft + (size_t)BHN * TDIM * PDIM);  // 64 KB
    float*  cmax = den + (size_t)BHN * TDIM;            // 64 KB
    float*  csum = cmax + (size_t)BHN * NCH * PDIM;     // 64 KB

    stats_kernel<<<BHN * NCH, 64, 0, stream>>>(K, cmax, csum);
    feat_kernel<<<BHN * NCH, 64, 0, stream>>>(Q, K, V, cmax, csum, Wf, Uf, Kft, den);
    attn_kernel<<<BHN * 16, 256, 0, stream>>>(Wf, Uf, Kft, den, out);
}

// Round 2
// 93.008 us; speedup vs baseline: 1.3008x; 1.3008x over previous
//
#include <hip/hip_runtime.h>
#include <hip/hip_bf16.h>

// Problem shape (fixed by setup_inputs): B=2, H=8, T=1024, P=64
#define TDIM 1024
#define PDIM 64
#define BHN  16     // B*H
#define NCH  64     // chunks along T
#define CHS  16     // chunk size (NCH*CHS == TDIM)

typedef __bf16 bf16_t;
typedef bf16_t bf16x8 __attribute__((ext_vector_type(8)));
typedef float  floatx4 __attribute__((ext_vector_type(4)));

__device__ __forceinline__ floatx4 mfma16(bf16x8 a, bf16x8 b, floatx4 c) {
    return __builtin_amdgcn_mfma_f32_16x16x32_bf16(a, b, c, 0, 0, 0);
}

// ---------------------------------------------------------------------------
// A1: per-(bh, chunk) stats: chunk max of K and chunk sum of exp(2K), per p.
// grid = BHN*NCH = 1024 blocks of 64 threads (lane = p) -> 4 waves/CU.
// All CHS loads issued up front (register prefetch), one vmcnt wait.
// ---------------------------------------------------------------------------
__global__ __launch_bounds__(64) void stats_kernel(
        const float* __restrict__ K,
        float* __restrict__ cmax, float* __restrict__ csum) {
    int bh = blockIdx.x >> 6;
    int c  = blockIdx.x & 63;
    int p  = threadIdx.x;
    const float* Kb = K + (size_t)bh * TDIM * PDIM + (size_t)c * CHS * PDIM + p;
    float k[CHS];
#pragma unroll
    for (int i = 0; i < CHS; ++i) k[i] = Kb[i * PDIM];
    float m = -INFINITY, s = 0.f;
#pragma unroll
    for (int i = 0; i < CHS; ++i) {
        m = fmaxf(m, k[i]);
        float e = __expf(k[i]);
        s += e * e;
    }
    cmax[(bh * NCH + c) * PDIM + p] = m;
    csum[(bh * NCH + c) * PDIM + p] = s;
}

// ---------------------------------------------------------------------------
// A2: seeded within-chunk sequential scan (CHS=16 steps). Emits:
//   W[bh][t][p]  = bf16( exp(Q - m_cum) )        (natural layout)
//   U[bh][t][p]  = bf16( V * exp(K) )            (natural layout)
//   Kft[bh][q][t]= bf16( exp(K[t][q]) )          (TRANSPOSED, via LDS tile)
//   den[bh][t]   = fp32 sum_p W*S2cum            (post-loop LDS reduce)
// grid = BHN*NCH = 1024 blocks of 64 threads (lane = p).
// ---------------------------------------------------------------------------
__global__ __launch_bounds__(64) void feat_kernel(
        const float* __restrict__ Q, const float* __restrict__ K,
        const float* __restrict__ V,
        const float* __restrict__ cmax, const float* __restrict__ csum,
        bf16_t* __restrict__ W, bf16_t* __restrict__ U,
        bf16_t* __restrict__ Kft, float* __restrict__ den) {
    int bh = blockIdx.x >> 6;
    int c  = blockIdx.x & 63;
    int p  = threadIdx.x;
    size_t base = (size_t)bh * TDIM * PDIM;
    int t0 = c * CHS;

    // chunk-prefix of (max, sum): up to 63 independent load pairs, pipelined
    float m = -INFINITY, s = 0.f;
#pragma unroll 8
    for (int cc = 0; cc < c; ++cc) {
        m = fmaxf(m, cmax[(bh * NCH + cc) * PDIM + p]);
        s += csum[(bh * NCH + cc) * PDIM + p];
    }

    // register-prefetch the whole chunk: 48 independent scalar loads in flight
    float kq[CHS], qq_[CHS], vv[CHS];
#pragma unroll
    for (int i = 0; i < CHS; ++i) {
        kq[i]  = K[base + (size_t)(t0 + i) * PDIM + p];
        qq_[i] = Q[base + (size_t)(t0 + i) * PDIM + p];
        vv[i]  = V[base + (size_t)(t0 + i) * PDIM + p];
    }

    __shared__ bf16_t ek_t[CHS][PDIM + 4];   // [t_local][p]
    __shared__ float  dt[CHS][PDIM + 1];     // per-(t,p) den contribution

#pragma unroll
    for (int i = 0; i < CHS; ++i) {
        int t = t0 + i;
        m = fmaxf(m, kq[i]);
        float ek = __expf(kq[i]);
        s += ek * ek;                         // inclusive running sum of exp(2K)
        float w = __expf(qq_[i] - m);         // inclusive running max
        W[base + (size_t)t * PDIM + p] = (bf16_t)w;
        U[base + (size_t)t * PDIM + p] = (bf16_t)(vv[i] * ek);
        ek_t[i][p] = (bf16_t)ek;
        dt[i][p] = w * s;
    }
    __syncthreads();

    // den reduce: lane l -> t = l>>2, g = l&3; partial over p = 4*i+g
    {
        int tl = p >> 2, g = p & 3;
        float d = 0.f;
#pragma unroll
        for (int i = 0; i < 16; ++i) d += dt[tl][i * 4 + g];
        d += __shfl_xor(d, 1);
        d += __shfl_xor(d, 2);
        if (g == 0) den[bh * TDIM + t0 + tl] = d;
    }

    // transposed Kft write: lanes (hi=p>>4, tl=p&15); 4 q-rows per iteration
    {
        int hi = p >> 4, tl = p & 15;
#pragma unroll
        for (int it = 0; it < 16; ++it) {
            int q = it * 4 + hi;
            Kft[((size_t)bh * PDIM + q) * TDIM + t0 + tl] = ek_t[tl][q];
        }
    }
}

// ---------------------------------------------------------------------------
// B: per-(bh, 64-row tile) causal double matmul.
//   phase1: C[t][t'] = sum_p W[t][p]*U[t'][p]       (MFMA NT, k = p)
//   mask + C -> LDS (bf16)
//   phase2: Y[t][q] += sum_t' C[t][t']*Kft[q][t']   (MFMA NT, k = t')
//   epilogue: Y /= (den + eps), store to out[b][t][h*64+q]
// grid = BHN*16 blocks of 256 threads (4 waves; wave w owns t-strip [16w,16w+16)).
// ---------------------------------------------------------------------------
__global__ __launch_bounds__(256) void attn_kernel(
        const bf16_t* __restrict__ W, const bf16_t* __restrict__ U,
        const bf16_t* __restrict__ Kft, const float* __restrict__ den,
        float* __restrict__ out) {
    int bh  = blockIdx.x & 15;
    int i   = blockIdx.x >> 4;   // row tile index 0..15
    int tid = threadIdx.x;
    int wave = tid >> 6, lane = tid & 63;
    int lq = lane & 15, qd = lane >> 4;
    int b = bh >> 3, h = bh & 7;

    __shared__ bf16_t Wt[64][72];
    __shared__ bf16_t Ut[64][72];
    __shared__ bf16_t Kt[64][72];
    __shared__ bf16_t Ct[64][72];
    __shared__ float  denb[64];

    size_t base = (size_t)bh * TDIM * PDIM;

    // stage W row-tile (8 KB contiguous) + den tile
    {
        const int4* gs = (const int4*)(W + base + (size_t)i * 64 * PDIM);
        for (int r = 0; r < 2; ++r) {
            int idx = tid + r * 256;
            int q = idx >> 3, s = idx & 7;
            *(int4*)&Wt[q][s * 8] = gs[idx];
        }
        if (tid < 64) denb[tid] = den[bh * TDIM + i * 64 + tid];
    }

    floatx4 acc[4];
    for (int j = 0; j < 4; ++j) acc[j] = (floatx4){0.f, 0.f, 0.f, 0.f};

    for (int kt = 0; kt <= i; ++kt) {
        __syncthreads();   // protect Ut/Kt (and first-iter Wt) vs prior phase2
        const int4* us = (const int4*)(U + base + (size_t)kt * 64 * PDIM);
        for (int r = 0; r < 2; ++r) {
            int idx = tid + r * 256;
            int q = idx >> 3, s = idx & 7;
            *(int4*)&Ut[q][s * 8] = us[idx];
            const int4* ks2 =
                (const int4*)(Kft + ((size_t)bh * PDIM + q) * TDIM + kt * 64);
            *(int4*)&Kt[q][s * 8] = ks2[s];
        }
        __syncthreads();

        // ---- phase 1: C strip (16 rows) = W_strip . U^T ----
        bf16x8 a0 = *(const bf16x8*)&Wt[wave * 16 + lq][qd * 8];
        bf16x8 a1 = *(const bf16x8*)&Wt[wave * 16 + lq][32 + qd * 8];
        floatx4 cc[4];
        for (int j = 0; j < 4; ++j) {
            bf16x8 b0 = *(const bf16x8*)&Ut[j * 16 + lq][qd * 8];
            bf16x8 b1 = *(const bf16x8*)&Ut[j * 16 + lq][32 + qd * 8];
            floatx4 t = (floatx4){0.f, 0.f, 0.f, 0.f};
            t = mfma16(a0, b0, t);
            t = mfma16(a1, b1, t);
            cc[j] = t;
        }

        // ---- causal mask + C -> LDS (C/D layout: row=quad*4+reg, col=lane&15)
        for (int j = 0; j < 4; ++j) {
            for (int r = 0; r < 4; ++r) {
                int trow = wave * 16 + qd * 4 + r;
                int tcol = j * 16 + lq;
                float v = cc[j][r];
                if (kt == i && tcol > trow) v = 0.f;
                Ct[trow][tcol] = (bf16_t)v;
            }
        }
        // each wave reads back only its own strip; same-wave LDS dep is
        // handled by compiler-inserted lgkmcnt waits.

        // ---- phase 2: Y_strip += C_strip . Kf ----
        for (int ks = 0; ks < 2; ++ks) {
            bf16x8 ca = *(const bf16x8*)&Ct[wave * 16 + lq][ks * 32 + qd * 8];
            for (int j = 0; j < 4; ++j) {
                bf16x8 kb = *(const bf16x8*)&Kt[j * 16 + lq][ks * 32 + qd * 8];
                acc[j] = mfma16(ca, kb, acc[j]);
            }
        }
    }

    // ---- epilogue: divide by den, store (out[b][t][h*64+q]) ----
    for (int j = 0; j < 4; ++j) {
        for (int r = 0; r < 4; ++r) {
            int trow = wave * 16 + qd * 4 + r;
            int tg = i * 64 + trow;
            float y = acc[j][r] / (denb[trow] + 1e-6f);
            out[((size_t)b * TDIM + tg) * (8 * PDIM) + h * PDIM + (j * 16 + lq)] = y;
        }
    }
}

// ---------------------------------------------------------------------------
extern "C" void kernel_launch(void* const* d_in, const int* in_sizes, int n_in,
                              void* d_out, int out_size, void* d_ws, size_t ws_size,
                              hipStream_t stream) {
    const float* Q = (const float*)d_in[0];
    const float* K = (const float*)d_in[1];
    const float* V = (const float*)d_in[2];
    float* out = (float*)d_out;

    // workspace layout (~6.8 MB total)
    bf16_t* Wf   = (bf16_t*)d_ws;                       // 2 MB
    bf16_t* Uf   = Wf + (size_t)BHN * TDIM * PDIM;      // 2 MB
    bf16_t* Kft  = Uf + (size_t)BHN * TDIM * PDIM;      // 2 MB
    float*  den  = (float*)(Kft + (size_t)BHN * TDIM * PDIM);  // 64 KB
    float*  cmax = den + (size_t)BHN * TDIM;            // 256 KB
    float*  csum = cmax + (size_t)BHN * NCH * PDIM;     // 256 KB

    stats_kernel<<<BHN * NCH, 64, 0, stream>>>(K, cmax, csum);
    feat_kernel<<<BHN * NCH, 64, 0, stream>>>(Q, K, V, cmax, csum, Wf, Uf, Kft, den);
    attn_kernel<<<BHN * 16, 256, 0, stream>>>(Wf, Uf, Kft, den, out);
}